// Round 5
// baseline (325.069 us; speedup 1.0000x reference)
//
#include <hip/hip_runtime.h>

#define NV 30000
#define MP 32
#define NB2 768
#define IT2 20

typedef short          s16x8 __attribute__((ext_vector_type(8)));
typedef float          f32x4 __attribute__((ext_vector_type(4)));

// f32 -> bf16 (RNE) bit-helper for init-time splits
__device__ __forceinline__ unsigned short bf16h(float f) {
    unsigned int u = __float_as_uint(f);
    return (unsigned short)((u + 0x7FFFu + ((u >> 16) & 1u)) >> 16);
}
__device__ __forceinline__ float bf16f(unsigned short h) {
    return __uint_as_float(((unsigned int)h) << 16);
}
// packed f32x2 -> bf16x2 in one instr (gfx950 v_cvt_pk_bf16_f32, T12)
__device__ __forceinline__ unsigned int cvtpk(float lo, float hi) {
    unsigned int r;
    asm("v_cvt_pk_bf16_f32 %0, %1, %2" : "=v"(r) : "v"(lo), "v"(hi));
    return r;
}

// Coalesced voxel stats: one wave per 2 voxels, lane&31 = point.
// vstat[n*8]: pmx,pmy,pmz,vmx,vmy,vmz,mdist,density
__global__ __launch_bounds__(256) void k_voxstats(
    const float* __restrict__ feats, const int* __restrict__ npts,
    float* __restrict__ vstat)
{
    const int gt = blockIdx.x*256 + threadIdx.x;
    const int lane = threadIdx.x & 63;
    const int m = lane & 31;
    const int vox = (gt >> 6)*2 + (lane >> 5);   // grid sized exactly
    const int np = npts[vox];
    const float4 p = ((const float4*)feats)[(size_t)vox*MP + m];
    const float msk = (m < np) ? 1.0f : 0.0f;
    float ux=p.x, uy=p.y, uz=p.z;
    float wx=p.x*msk, wy=p.y*msk, wz=p.z*msk;
    #pragma unroll
    for (int off=1; off<32; off<<=1) {
        ux += __shfl_xor(ux,off); uy += __shfl_xor(uy,off); uz += __shfl_xor(uz,off);
        wx += __shfl_xor(wx,off); wy += __shfl_xor(wy,off); wz += __shfl_xor(wz,off);
    }
    const float fnp = (float)np;                 // np >= 1 always
    const float vmx = wx/fnp, vmy = wy/fnp, vmz = wz/fnp;
    const float dx = p.x-vmx, dy = p.y-vmy, dz = p.z-vmz;
    float d = sqrtf(dx*dx+dy*dy+dz*dz)*msk;
    #pragma unroll
    for (int off=1; off<32; off<<=1) d += __shfl_xor(d,off);
    if (m == 0) {
        float* o = vstat + (size_t)vox*8;
        *(float4*)o       = make_float4(ux/fnp, uy/fnp, uz/fnp, vmx);
        *(float4*)(o + 4) = make_float4(vmy, vmz, d/fnp, fnp/0.16f);
    }
}

// GEMM1 (13->64) fp32: per-voxel raw min/max of h1 + global sum/sumsq (f64).
#define G1B 1024
__global__ __launch_bounds__(256) void k_gemm1(
    const float* __restrict__ feats, const int* __restrict__ npts,
    const int* __restrict__ coors, const float* __restrict__ vstat,
    const float* __restrict__ W1,
    float* __restrict__ vmax1, float* __restrict__ vmin1,
    double* __restrict__ sum1, double* __restrict__ sumsq1)
{
    __shared__ float xls[4][MP][15];
    __shared__ double red[4][64];
    const int wave = threadIdx.x >> 6;
    const int lane = threadIdx.x & 63;
    float w1c[13];
    #pragma unroll
    for (int k=0;k<13;++k) w1c[k] = W1[k*64 + lane];
    double dsum = 0.0, dsq = 0.0;
    const int iters = (NV + G1B*4 - 1) / (G1B*4);
    for (int it=0; it<iters; ++it) {
        int n = (it*G1B + blockIdx.x)*4 + wave;
        bool act = (n < NV);
        if (act && lane < MP) {
            int np = npts[n];
            float cx = (float)coors[n*4+3]*0.2f + 0.1f;
            float cy = (float)coors[n*4+2]*0.2f - 39.9f;
            float cz = (float)coors[n*4+1]*4.0f - 1.0f;
            const float* vs = vstat + (size_t)n*8;
            float4 p = ((const float4*)feats)[(size_t)n*MP + lane];
            float msk = (lane < np) ? 1.0f : 0.0f;
            float xv[13];
            xv[0]=p.x*msk; xv[1]=p.y*msk; xv[2]=p.z*msk; xv[3]=p.w*msk;
            xv[4]=(p.x-vs[0])*msk; xv[5]=(p.y-vs[1])*msk; xv[6]=(p.z-vs[2])*msk;
            xv[7]=(p.x-cx)*msk; xv[8]=(p.y-cy)*msk; xv[9]=(p.z-cz)*msk;
            xv[10]=sqrtf(p.x*p.x+p.y*p.y+p.z*p.z)*msk;
            xv[11]=vs[7]*msk; xv[12]=vs[6]*msk;
            #pragma unroll
            for (int k=0;k<13;++k) xls[wave][lane][k] = xv[k];
        }
        __syncthreads();
        if (act) {
            float hmax = -3.402823466e38f, hmin = 3.402823466e38f;
            float lsum = 0.f, lsq = 0.f;
            #pragma unroll 4
            for (int m=0;m<MP;++m) {
                float h = 0.f;
                #pragma unroll
                for (int k=0;k<13;++k) h = fmaf(xls[wave][m][k], w1c[k], h);
                hmax = fmaxf(hmax, h); hmin = fminf(hmin, h);
                lsum += h; lsq = fmaf(h, h, lsq);
            }
            vmax1[(size_t)n*64 + lane] = hmax;
            vmin1[(size_t)n*64 + lane] = hmin;
            dsum += (double)lsum; dsq += (double)lsq;
        }
        __syncthreads();
    }
    red[wave][lane] = dsum;
    __syncthreads();
    if (wave == 0) atomicAdd(&sum1[lane], red[0][lane]+red[1][lane]+red[2][lane]+red[3][lane]);
    __syncthreads();
    red[wave][lane] = dsq;
    __syncthreads();
    if (wave == 0) atomicAdd(&sumsq1[lane], red[0][lane]+red[1][lane]+red[2][lane]+red[3][lane]);
}

__global__ void k_fin1(const double* __restrict__ sum1, const double* __restrict__ sumsq1,
                       const float* __restrict__ g1, const float* __restrict__ b1,
                       float* __restrict__ sc1, float* __restrict__ sh1) {
    int c = threadIdx.x;
    if (c >= 64) return;
    double cnt = (double)NV * MP;
    double mu = sum1[c]/cnt;
    double var = sumsq1[c]/cnt - mu*mu;
    double rs = 1.0 / sqrt(var + 1e-3);
    double sc = (double)g1[c]*rs;
    sc1[c] = (float)sc;
    sh1[c] = (float)((double)b1[c] - mu*sc);
}

// t[v][c] = agg[v][0:64] @ W2[64:128][c]  (agg from vmax1/vmin1 monotone trick)
__global__ __launch_bounds__(256) void k_aggt(
    const float* __restrict__ vmax1, const float* __restrict__ vmin1,
    const float* __restrict__ sc1, const float* __restrict__ sh1,
    const float* __restrict__ W2, float* __restrict__ tbuf)
{
    __shared__ float w2T[128][68];   // transposed W2b, padded (68 = 4*17)
    __shared__ float aggls[2][64];
    const int t = threadIdx.x;
    for (int i = t; i < 128*64; i += 256) {
        int k = i >> 7, c = i & 127;
        w2T[c][k] = W2[(64+k)*128 + c];
    }
    __syncthreads();
    const int v2 = t >> 7, c = t & 127;
    const int iters = (NV/2 + 255) / 256;
    for (int it=0; it<iters; ++it) {
        int pair = it*256 + blockIdx.x;
        bool act = pair < NV/2;
        if (act && t < 128) {
            int vv = t >> 6, k = t & 63;
            float s = sc1[k];
            size_t o = (size_t)(pair*2+vv)*64 + k;
            float v = (s >= 0.f) ? vmax1[o] : vmin1[o];
            aggls[vv][k] = fmaxf(fmaf(v, s, sh1[k]), 0.f);
        }
        __syncthreads();
        if (act) {
            float acc = 0.f;
            #pragma unroll
            for (int k4=0; k4<64; k4+=4) {
                float4 a = *(const float4*)&aggls[v2][k4];
                float4 wv = *(const float4*)&w2T[c][k4];
                acc = fmaf(a.x,wv.x,acc); acc = fmaf(a.y,wv.y,acc);
                acc = fmaf(a.z,wv.z,acc); acc = fmaf(a.w,wv.w,acc);
            }
            tbuf[(size_t)(pair*2+v2)*128 + c] = acc;
        }
        __syncthreads();
    }
}

// ---------------------------------------------------------------------------
// GEMM2, K=64 (agg hoisted to tbuf). 256 thr, 2 voxels (M=64) x N=128.
// h1 computed as h1^T = W1'(.sc-folded) @ x1^T via swapped MFMA: C/D lane=point,
// regs=channel -> contiguous-k u16x4 packs straight into swizzled x2 LDS.
// GEMM2: 3-pass bf16 hi/lo, wave w owns N-slice w*32..+32, W2a frags in regs.
// Epilogue adds t[v][c] (constant per voxel) to max/min and stats.
// ---------------------------------------------------------------------------
__global__ __launch_bounds__(256, 2) void k_gemm2(
    const float* __restrict__ feats, const int* __restrict__ npts,
    const int* __restrict__ coors, const float* __restrict__ vstat,
    const float* __restrict__ W1, const float* __restrict__ W2,
    const float* __restrict__ sc1, const float* __restrict__ sh1,
    const float* __restrict__ tbuf,
    float* __restrict__ vmax2, float* __restrict__ vmin2,
    double* __restrict__ sum2, double* __restrict__ sumsq2)
{
    __shared__ unsigned short x1h[64*32];   // point-rows x k(0..31, >=13 zero)
    __shared__ unsigned short x1l[64*32];
    __shared__ unsigned short x2h[64*64];
    __shared__ unsigned short x2l[64*64];
    __shared__ float tls[2][128];

    const int t = threadIdx.x;
    const int lane = t & 63;
    const int w = t >> 6;
    const int lr = lane & 15;
    const int g  = lane >> 4;

    // zero x1 planes once (pad slots must stay 0; stage never rewrites them)
    for (int i = t; i < 64*32/8; i += 256) {
        ((uint4*)x1h)[i] = make_uint4(0,0,0,0);
        ((uint4*)x1l)[i] = make_uint4(0,0,0,0);
    }

    // W2a (rows 0..63) B-fragments hi/lo
    s16x8 Bh[2][2], Bl[2][2];
    {
        const int col0 = w*32 + lr;
        const int kq = g*8;
        #pragma unroll
        for (int nt=0; nt<2; ++nt)
            #pragma unroll
            for (int ks=0; ks<2; ++ks)
                #pragma unroll
                for (int j=0; j<8; ++j) {
                    float v = W2[(ks*32 + kq + j)*128 + col0 + nt*16];
                    unsigned short h = bf16h(v);
                    Bh[nt][ks][j] = (short)h;
                    Bl[nt][ks][j] = (short)bf16h(v - bf16f(h));
                }
    }
    // W1' A-fragments (h1^T): A[ch][k] = W1[k][ch]*sc1[ch], k>=13 -> 0
    s16x8 Wh[4], Wl[4];
    float shr[4][4];
    #pragma unroll
    for (int ct=0; ct<4; ++ct) {
        const int ch = ct*16 + lr;
        const float scv = sc1[ch];
        #pragma unroll
        for (int j=0; j<8; ++j) {
            int k = g*8 + j;
            float v = (k < 13) ? W1[k*64 + ch]*scv : 0.f;
            unsigned short h = bf16h(v);
            Wh[ct][j] = (short)h;
            Wl[ct][j] = (short)bf16h(v - bf16f(h));
        }
        #pragma unroll
        for (int r=0; r<4; ++r) shr[ct][r] = sh1[ct*16 + g*4 + r];
    }

    const int myrow = w*16 + lr;            // this wave's point rows
    const int swx = (myrow & 3) << 3;       // x1 swizzle (row = 32 elem)
    const int swp = (myrow & 7) << 3;       // x2 swizzle (row = 64 elem)
    double dsum[2] = {0.0,0.0}, dsq[2] = {0.0,0.0};
    __syncthreads();

    for (int it=0; it<IT2; ++it) {
        const int pair = it*NB2 + blockIdx.x;
        const bool act = pair < NV/2;
        const int vox0 = pair*2;

        // ---- stage: tls + x1 (hi/lo bf16, wave-private rows) ----
        if (act) {
            tls[t>>7][t&127] = tbuf[(size_t)(vox0 + (t>>7))*128 + (t&127)];
            if (g == 0) {
                const int vox = vox0 + (myrow >> 5);
                const int np = npts[vox];
                const float cx = (float)coors[vox*4+3]*0.2f + 0.1f;
                const float cy = (float)coors[vox*4+2]*0.2f - 39.9f;
                const float cz = (float)coors[vox*4+1]*4.0f - 1.0f;
                const float4 vsa = *(const float4*)&vstat[(size_t)vox*8];
                const float4 vsb = *(const float4*)&vstat[(size_t)vox*8+4];
                const int m = myrow & 31;
                const float4 p = ((const float4*)feats)[(size_t)vox*MP + m];
                const float msk = (m < np) ? 1.0f : 0.0f;
                float xv[16];
                xv[0]=p.x*msk; xv[1]=p.y*msk; xv[2]=p.z*msk; xv[3]=p.w*msk;
                xv[4]=(p.x-vsa.x)*msk; xv[5]=(p.y-vsa.y)*msk; xv[6]=(p.z-vsa.z)*msk;
                xv[7]=(p.x-cx)*msk; xv[8]=(p.y-cy)*msk; xv[9]=(p.z-cz)*msk;
                xv[10]=sqrtf(p.x*p.x+p.y*p.y+p.z*p.z)*msk;
                xv[11]=vsb.w*msk; xv[12]=vsb.z*msk;
                xv[13]=0.f; xv[14]=0.f; xv[15]=0.f;
                unsigned int hu[8], lu[8];
                #pragma unroll
                for (int j=0;j<8;++j) {
                    unsigned int hw = cvtpk(xv[2*j], xv[2*j+1]);
                    float f0 = __uint_as_float(hw << 16);
                    float f1 = __uint_as_float(hw & 0xffff0000u);
                    lu[j] = cvtpk(xv[2*j]-f0, xv[2*j+1]-f1);
                    hu[j] = hw;
                }
                const int e0 = myrow*32 + swx;          // elems 0..7 slot
                const int e1 = myrow*32 + (8 ^ swx);    // elems 8..15 slot
                *(uint4*)&x1h[e0] = make_uint4(hu[0],hu[1],hu[2],hu[3]);
                *(uint4*)&x1h[e1] = make_uint4(hu[4],hu[5],hu[6],hu[7]);
                *(uint4*)&x1l[e0] = make_uint4(lu[0],lu[1],lu[2],lu[3]);
                *(uint4*)&x1l[e1] = make_uint4(lu[4],lu[5],lu[6],lu[7]);
            }
        }
        asm volatile("s_waitcnt lgkmcnt(0)" ::: "memory");  // same-wave x1 RAW

        // ---- h1 phase: h1^T = W1' @ x1^T, 3-pass, write x2 hi/lo ----
        if (act) {
            const int be = (myrow*32 + g*8) ^ swx;
            s16x8 xh = *(const s16x8*)&x1h[be];
            s16x8 xl = *(const s16x8*)&x1l[be];
            #pragma unroll
            for (int ct=0; ct<4; ++ct) {
                f32x4 hv;
                hv[0]=shr[ct][0]; hv[1]=shr[ct][1]; hv[2]=shr[ct][2]; hv[3]=shr[ct][3];
                hv = __builtin_amdgcn_mfma_f32_16x16x32_bf16(Wh[ct], xh, hv, 0,0,0);
                hv = __builtin_amdgcn_mfma_f32_16x16x32_bf16(Wh[ct], xl, hv, 0,0,0);
                hv = __builtin_amdgcn_mfma_f32_16x16x32_bf16(Wl[ct], xh, hv, 0,0,0);
                float a0 = fmaxf(hv[0],0.f), a1 = fmaxf(hv[1],0.f);
                float a2 = fmaxf(hv[2],0.f), a3 = fmaxf(hv[3],0.f);
                unsigned int h01 = cvtpk(a0,a1), h23 = cvtpk(a2,a3);
                float r0 = a0 - __uint_as_float(h01<<16);
                float r1 = a1 - __uint_as_float(h01 & 0xffff0000u);
                float r2 = a2 - __uint_as_float(h23<<16);
                float r3 = a3 - __uint_as_float(h23 & 0xffff0000u);
                unsigned int l01 = cvtpk(r0,r1), l23 = cvtpk(r2,r3);
                const int e = (myrow*64 + ct*16 + g*4) ^ swp;
                *(uint2*)&x2h[e] = make_uint2(h01,h23);
                *(uint2*)&x2l[e] = make_uint2(l01,l23);
            }
        }
        __syncthreads();   // x2 + tls ready

        // ---- GEMM2 MFMA: K=64, 3-pass ----
        f32x4 acc[4][2];
        float tv[2][2];
        if (act) {
            #pragma unroll
            for (int v=0; v<2; ++v)
                #pragma unroll
                for (int nt=0; nt<2; ++nt)
                    tv[v][nt] = tls[v][w*32 + nt*16 + lr];
            #pragma unroll
            for (int mt=0;mt<4;++mt)
                #pragma unroll
                for (int nt=0;nt<2;++nt) {
                    acc[mt][nt][0]=0.f; acc[mt][nt][1]=0.f;
                    acc[mt][nt][2]=0.f; acc[mt][nt][3]=0.f;
                }
            #pragma unroll
            for (int ks=0; ks<2; ++ks) {
                s16x8 Ah[4], Al[4];
                #pragma unroll
                for (int mt=0;mt<4;++mt) {
                    const int p = mt*16 + lr;
                    const int e = (p*64 + ks*32 + g*8) ^ ((p&7)<<3);
                    Ah[mt] = *(const s16x8*)&x2h[e];
                    Al[mt] = *(const s16x8*)&x2l[e];
                }
                #pragma unroll
                for (int mt=0;mt<4;++mt)
                    #pragma unroll
                    for (int nt=0;nt<2;++nt) {
                        acc[mt][nt] = __builtin_amdgcn_mfma_f32_16x16x32_bf16(Ah[mt], Bh[nt][ks], acc[mt][nt], 0,0,0);
                        acc[mt][nt] = __builtin_amdgcn_mfma_f32_16x16x32_bf16(Al[mt], Bh[nt][ks], acc[mt][nt], 0,0,0);
                        acc[mt][nt] = __builtin_amdgcn_mfma_f32_16x16x32_bf16(Ah[mt], Bl[nt][ks], acc[mt][nt], 0,0,0);
                    }
            }
        }
        __syncthreads();   // x2 reads done; next iter may overwrite

        // ---- epilogue: +t, per-voxel max/min, stats ----
        if (act) {
            #pragma unroll
            for (int v=0; v<2; ++v) {
                #pragma unroll
                for (int nt=0; nt<2; ++nt) {
                    const f32x4 qa = acc[2*v][nt], qb = acc[2*v+1][nt];
                    float mx = fmaxf(fmaxf(fmaxf(qa[0],qa[1]), fmaxf(qa[2],qa[3])),
                                     fmaxf(fmaxf(qb[0],qb[1]), fmaxf(qb[2],qb[3])));
                    float mn = fminf(fminf(fminf(qa[0],qa[1]), fminf(qa[2],qa[3])),
                                     fminf(fminf(qb[0],qb[1]), fminf(qb[2],qb[3])));
                    mx = fmaxf(mx, __shfl_xor(mx, 16)); mn = fminf(mn, __shfl_xor(mn, 16));
                    mx = fmaxf(mx, __shfl_xor(mx, 32)); mn = fminf(mn, __shfl_xor(mn, 32));
                    if (lane < 16) {
                        const size_t o = (size_t)(vox0 + v)*128 + w*32 + nt*16 + lane;
                        vmax2[o] = mx + tv[v][nt];
                        vmin2[o] = mn + tv[v][nt];
                    }
                    float s = 0.f, q = 0.f;
                    #pragma unroll
                    for (int r=0;r<4;++r) {
                        float ea = qa[r] + tv[v][nt];
                        float eb = qb[r] + tv[v][nt];
                        s += ea + eb;
                        q = fmaf(ea, ea, fmaf(eb, eb, q));
                    }
                    dsum[nt] += (double)s; dsq[nt] += (double)q;
                }
            }
        }
    }

    // ---- global BN2 stats ----
    #pragma unroll
    for (int nt=0; nt<2; ++nt) {
        double s = dsum[nt], q = dsq[nt];
        s += __shfl_xor(s, 16); q += __shfl_xor(q, 16);
        s += __shfl_xor(s, 32); q += __shfl_xor(q, 32);
        if (lane < 16) {
            atomicAdd(&sum2[w*32 + nt*16 + lane], s);
            atomicAdd(&sumsq2[w*32 + nt*16 + lane], q);
        }
    }
}

__global__ void k_fin2(const double* __restrict__ sum2, const double* __restrict__ sumsq2,
                       const float* __restrict__ g2, const float* __restrict__ b2,
                       float* __restrict__ sc2, float* __restrict__ sh2) {
    int c = threadIdx.x;
    if (c >= 128) return;
    double cnt = (double)NV * MP;
    double mu = sum2[c]/cnt;
    double var = sumsq2[c]/cnt - mu*mu;
    double rs = 1.0 / sqrt(var + 1e-3);
    double sc = (double)g2[c]*rs;
    sc2[c] = (float)sc;
    sh2[c] = (float)((double)b2[c] - mu*sc);
}

__global__ void k_out(const float* __restrict__ vmax2, const float* __restrict__ vmin2,
                      const float* __restrict__ sc2, const float* __restrict__ sh2,
                      float* __restrict__ out) {
    int t = blockIdx.x*blockDim.x + threadIdx.x;
    if (t >= NV*128) return;
    int c = t & 127;
    float s = sc2[c];
    float v = (s >= 0.f) ? vmax2[t] : vmin2[t];
    out[t] = fmaxf(fmaf(v, s, sh2[c]), 0.f);
}

extern "C" void kernel_launch(void* const* d_in, const int* in_sizes, int n_in,
                              void* d_out, int out_size, void* d_ws, size_t ws_size,
                              hipStream_t stream) {
    const float* feats = (const float*)d_in[0];
    const int*   npts  = (const int*)d_in[1];
    const int*   coors = (const int*)d_in[2];
    const float* W1    = (const float*)d_in[3];
    const float* g1    = (const float*)d_in[4];
    const float* b1    = (const float*)d_in[5];
    const float* W2    = (const float*)d_in[6];
    const float* g2    = (const float*)d_in[7];
    const float* b2    = (const float*)d_in[8];
    float* out = (float*)d_out;

    double* sum1   = (double*)d_ws;            // 64
    double* sumsq1 = sum1 + 64;                // 64
    double* sum2   = sumsq1 + 64;              // 128
    double* sumsq2 = sum2 + 128;               // 128 (384 doubles)
    float* fb = (float*)(sumsq2 + 128);
    float* vstat = fb;            fb += (size_t)NV*8;
    float* vmax1 = fb;            fb += (size_t)NV*64;
    float* vmin1 = fb;            fb += (size_t)NV*64;
    float* vmax2 = fb;            fb += (size_t)NV*128;
    float* vmin2 = fb;            fb += (size_t)NV*128;
    float* tbuf  = fb;            fb += (size_t)NV*128;
    float* sc1 = fb;              fb += 64;
    float* sh1 = fb;              fb += 64;
    float* sc2 = fb;              fb += 128;
    float* sh2 = fb;              fb += 128;

    hipMemsetAsync(d_ws, 0, 384*sizeof(double), stream);
    hipLaunchKernelGGL(k_voxstats, dim3(3750), dim3(256), 0, stream,
                       feats, npts, vstat);
    hipLaunchKernelGGL(k_gemm1, dim3(G1B), dim3(256), 0, stream,
                       feats, npts, coors, vstat, W1, vmax1, vmin1, sum1, sumsq1);
    hipLaunchKernelGGL(k_fin1, dim3(1), dim3(64), 0, stream,
                       sum1, sumsq1, g1, b1, sc1, sh1);
    hipLaunchKernelGGL(k_aggt, dim3(256), dim3(256), 0, stream,
                       vmax1, vmin1, sc1, sh1, W2, tbuf);
    hipLaunchKernelGGL(k_gemm2, dim3(NB2), dim3(256), 0, stream,
                       feats, npts, coors, vstat, W1, W2, sc1, sh1, tbuf,
                       vmax2, vmin2, sum2, sumsq2);
    hipLaunchKernelGGL(k_fin2, dim3(1), dim3(128), 0, stream,
                       sum2, sumsq2, g2, b2, sc2, sh2);
    hipLaunchKernelGGL(k_out, dim3(NV*128/256), dim3(256), 0, stream,
                       vmax2, vmin2, sc2, sh2, out);
}